// Round 1
// baseline (253.428 us; speedup 1.0000x reference)
//
#include <hip/hip_runtime.h>
#include <math.h>

// RangeAwareL1Loss on MI355X.
// ws layout: [0..30] uint bin counts, [31] uint valid count, byte 128+: float partials[NBLK].

#define NBLK 2048
#define NTHR 256

__global__ __launch_bounds__(256) void hist_kernel(const float* __restrict__ target,
                                                   unsigned int* __restrict__ g_counts,
                                                   int n4) {
    __shared__ unsigned int lhist[4][30];   // per-wave sub-histograms, bins 0..29
    const int tid  = threadIdx.x;
    const int wid  = tid >> 6;
    const int lane = tid & 63;

    for (int i = tid; i < 4 * 30; i += 256) ((unsigned int*)lhist)[i] = 0u;
    __syncthreads();

    unsigned int c30 = 0, cval = 0;
    const float4* t4 = (const float4*)target;
    for (long long i = (long long)blockIdx.x * 256 + tid; i < n4;
         i += (long long)gridDim.x * 256) {
        float4 v = t4[i];
#pragma unroll
        for (int e = 0; e < 4; ++e) {
            float t = (&v.x)[e];
            cval += (t != -1.0f) ? 1u : 0u;
            if (t >= 0.0f) {                    // in_range == (t >= 0): expm1 monotone
                float nat = expm1f(t);
                if (nat >= 30.0f) c30++;        // hot bin -> register, avoids LDS hotspot
                else atomicAdd(&lhist[wid][(int)nat], 1u);
            }
        }
    }
    // wave-reduce register counters
#pragma unroll
    for (int off = 32; off > 0; off >>= 1) {
        c30  += __shfl_down(c30,  off, 64);
        cval += __shfl_down(cval, off, 64);
    }
    if (lane == 0) {
        atomicAdd(&g_counts[30], c30);
        atomicAdd(&g_counts[31], cval);
    }
    __syncthreads();
    if (tid < 30) {
        unsigned int s = lhist[0][tid] + lhist[1][tid] + lhist[2][tid] + lhist[3][tid];
        atomicAdd(&g_counts[tid], s);
    }
}

__global__ __launch_bounds__(256) void wsum_kernel(const float* __restrict__ pred,
                                                   const float* __restrict__ target,
                                                   const unsigned int* __restrict__ g_counts,
                                                   float* __restrict__ partials,
                                                   int n4) {
    __shared__ float w_s[31];
    __shared__ float red[4];
    const int tid = threadIdx.x;
    if (tid < 31) {
        float tv   = (float)g_counts[31];
        float freq = (float)g_counts[tid] / tv;
        w_s[tid]   = 1.0f / (sqrtf(freq) + 1e-6f);   // ALPHA=0.5, EPS=1e-6
    }
    __syncthreads();

    float s = 0.0f;
    const float4* t4 = (const float4*)target;
    const float4* p4 = (const float4*)pred;
    for (long long i = (long long)blockIdx.x * 256 + tid; i < n4;
         i += (long long)gridDim.x * 256) {
        float4 tv4 = t4[i];
        float4 pv4 = p4[i];
#pragma unroll
        for (int e = 0; e < 4; ++e) {
            float t = (&tv4.x)[e];
            float p = (&pv4.x)[e];
            if (t >= 0.0f) {
                float nat = expm1f(t);
                int   b   = (nat >= 30.0f) ? 30 : (int)nat;
                s += fabsf(p - t) * w_s[b];          // 31 distinct banks; dup bins broadcast
            }
        }
    }
#pragma unroll
    for (int off = 32; off > 0; off >>= 1) s += __shfl_down(s, off, 64);
    const int wid = tid >> 6, lane = tid & 63;
    if (lane == 0) red[wid] = s;
    __syncthreads();
    if (tid == 0) partials[blockIdx.x] = red[0] + red[1] + red[2] + red[3];
}

__global__ __launch_bounds__(256) void final_kernel(const float* __restrict__ partials,
                                                    const unsigned int* __restrict__ g_counts,
                                                    float* __restrict__ out, int nblk) {
    __shared__ float red[4];
    const int tid = threadIdx.x;
    float s = 0.0f;
    for (int i = tid; i < nblk; i += 256) s += partials[i];
#pragma unroll
    for (int off = 32; off > 0; off >>= 1) s += __shfl_down(s, off, 64);
    if ((tid & 63) == 0) red[tid >> 6] = s;
    __syncthreads();
    if (tid == 0) out[0] = (red[0] + red[1] + red[2] + red[3]) / (float)g_counts[31];
}

extern "C" void kernel_launch(void* const* d_in, const int* in_sizes, int n_in,
                              void* d_out, int out_size, void* d_ws, size_t ws_size,
                              hipStream_t stream) {
    const float* pred   = (const float*)d_in[0];
    const float* target = (const float*)d_in[1];
    float*       out    = (float*)d_out;

    unsigned int* g_counts = (unsigned int*)d_ws;              // 32 uints
    float*        partials = (float*)((char*)d_ws + 128);      // NBLK floats

    const int n  = in_sizes[0];    // 64*512*512 = 16,777,216 (divisible by 4)
    const int n4 = n / 4;

    hipMemsetAsync(d_ws, 0, 128, stream);                      // zero counts each call
    hist_kernel<<<NBLK, NTHR, 0, stream>>>(target, g_counts, n4);
    wsum_kernel<<<NBLK, NTHR, 0, stream>>>(pred, target, g_counts, partials, n4);
    final_kernel<<<1, NTHR, 0, stream>>>(partials, g_counts, out, NBLK);
}

// Round 2
// 89.528 us; speedup vs baseline: 2.8307x; 2.8307x over previous
//
#include <hip/hip_runtime.h>
#include <math.h>

// RangeAwareL1Loss on MI355X.
// ws layout: [0..30] uint bin counts, [31] uint valid count, byte 128+: float partials[NBLK].

#define NBLK 2048
#define NTHR 256
#define HSTRIDE 34   // u16 elements per thread row; (34*t+b)*2/4 % 32 = 17t+(b>>1) mod 32 -> exactly 2-way (free)

// fast bin: for t >= 0, floor(expm1(t)) == floor(exp(t)) - 1 == (int)exp2(t*log2e) - 1
__device__ __forceinline__ int fast_bin(float t) {
    float ex = __builtin_amdgcn_exp2f(t * 1.4426950408889634f);  // e^t, >= 1 for t >= 0
    int b = (int)ex - 1;          // v_cvt saturates on overflow; t<=log1p(40) in practice
    return (b > 30) ? 30 : b;
}

__global__ __launch_bounds__(256) void hist_kernel(const float* __restrict__ target,
                                                   unsigned int* __restrict__ g_counts,
                                                   int n4) {
    __shared__ unsigned short lh[NTHR * HSTRIDE];  // per-THREAD privatized rows: no atomics
    __shared__ unsigned int part[8][32];
    __shared__ unsigned int vpart[4];
    const int tid = threadIdx.x;

    // zero my own row (17 dwords == 34 u16); no sync needed, rows are thread-private
    unsigned int* lhw = (unsigned int*)lh;
#pragma unroll
    for (int k = 0; k < 17; ++k) lhw[tid * 17 + k] = 0u;

    unsigned int cval = 0;
    const float4* t4 = (const float4*)target;
    const int tbase = tid * HSTRIDE;
    for (int i = blockIdx.x * NTHR + tid; i < n4; i += NBLK * NTHR) {
        float4 v = t4[i];
#pragma unroll
        for (int e = 0; e < 4; ++e) {
            float t = (&v.x)[e];
            cval += (t != -1.0f) ? 1u : 0u;
            if (t >= 0.0f) {                     // exec-masked; no atomic, thread-own row
                lh[tbase + fast_bin(t)] += 1;
            }
        }
    }

    __syncthreads();
    // stage 1: 8 groups x 31 bins; group g sums threads [g*32, g*32+32)
    {
        int b = tid & 31, g = tid >> 5;
        if (b < 31) {
            unsigned int s = 0;
#pragma unroll 8
            for (int r = g * 32; r < g * 32 + 32; ++r) s += lh[r * HSTRIDE + b];
            part[g][b] = s;
        }
    }
    // valid count: wave shuffle reduce
#pragma unroll
    for (int off = 32; off > 0; off >>= 1) cval += __shfl_down(cval, off, 64);
    if ((tid & 63) == 0) vpart[tid >> 6] = cval;
    __syncthreads();
    if (tid < 31) {
        unsigned int s = 0;
#pragma unroll
        for (int g2 = 0; g2 < 8; ++g2) s += part[g2][tid];
        atomicAdd(&g_counts[tid], s);
    }
    if (tid == 32) atomicAdd(&g_counts[31], vpart[0] + vpart[1] + vpart[2] + vpart[3]);
}

__global__ __launch_bounds__(256) void wsum_kernel(const float* __restrict__ pred,
                                                   const float* __restrict__ target,
                                                   const unsigned int* __restrict__ g_counts,
                                                   float* __restrict__ partials,
                                                   int n4) {
    __shared__ float w_s[31];
    __shared__ float red[4];
    const int tid = threadIdx.x;
    if (tid < 31) {
        float tv   = (float)g_counts[31];
        float freq = (float)g_counts[tid] / tv;
        w_s[tid]   = 1.0f / (sqrtf(freq) + 1e-6f);   // ALPHA=0.5, EPS=1e-6
    }
    __syncthreads();

    float s = 0.0f;
    const float4* t4 = (const float4*)target;
    const float4* p4 = (const float4*)pred;
    for (int i = blockIdx.x * NTHR + tid; i < n4; i += NBLK * NTHR) {
        float4 tv4 = t4[i];
        float4 pv4 = p4[i];
#pragma unroll
        for (int e = 0; e < 4; ++e) {
            float t = (&tv4.x)[e];
            float p = (&pv4.x)[e];
            if (t >= 0.0f) {
                s += fabsf(p - t) * w_s[fast_bin(t)];  // <=2 lanes/bank + broadcast: free
            }
        }
    }
#pragma unroll
    for (int off = 32; off > 0; off >>= 1) s += __shfl_down(s, off, 64);
    if ((tid & 63) == 0) red[tid >> 6] = s;
    __syncthreads();
    if (tid == 0) partials[blockIdx.x] = red[0] + red[1] + red[2] + red[3];
}

__global__ __launch_bounds__(256) void final_kernel(const float* __restrict__ partials,
                                                    const unsigned int* __restrict__ g_counts,
                                                    float* __restrict__ out, int nblk) {
    __shared__ float red[4];
    const int tid = threadIdx.x;
    float s = 0.0f;
    for (int i = tid; i < nblk; i += 256) s += partials[i];
#pragma unroll
    for (int off = 32; off > 0; off >>= 1) s += __shfl_down(s, off, 64);
    if ((tid & 63) == 0) red[tid >> 6] = s;
    __syncthreads();
    if (tid == 0) out[0] = (red[0] + red[1] + red[2] + red[3]) / (float)g_counts[31];
}

extern "C" void kernel_launch(void* const* d_in, const int* in_sizes, int n_in,
                              void* d_out, int out_size, void* d_ws, size_t ws_size,
                              hipStream_t stream) {
    const float* pred   = (const float*)d_in[0];
    const float* target = (const float*)d_in[1];
    float*       out    = (float*)d_out;

    unsigned int* g_counts = (unsigned int*)d_ws;              // 32 uints
    float*        partials = (float*)((char*)d_ws + 128);      // NBLK floats

    const int n  = in_sizes[0];    // 16,777,216; NBLK*NTHR*4 divides n exactly
    const int n4 = n / 4;

    hipMemsetAsync(d_ws, 0, 128, stream);                      // zero counts each call
    hist_kernel<<<NBLK, NTHR, 0, stream>>>(target, g_counts, n4);
    wsum_kernel<<<NBLK, NTHR, 0, stream>>>(pred, target, g_counts, partials, n4);
    final_kernel<<<1, NTHR, 0, stream>>>(partials, g_counts, out, NBLK);
}

// Round 3
// 89.294 us; speedup vs baseline: 2.8381x; 1.0026x over previous
//
#include <hip/hip_runtime.h>
#include <math.h>

// RangeAwareL1Loss on MI355X.
// ws layout: [0..30] uint bin counts, [31] uint valid count, byte 128+: float partials[NBLK].

#define NBLK 2048
#define NTHR 256
#define NROW 128     // per-thread-PAIR rows (tid & 127); cross-wave sharing is atomic-safe
#define HS   33      // u32 stride: bank = (row + b) % 32 -> ~2 lanes/bank (free)

// fast bin: for t >= 0, floor(expm1(t)) == floor(exp(t)) - 1 == (int)exp2(t*log2e) - 1
__device__ __forceinline__ int fast_bin(float t) {
    float ex = __builtin_amdgcn_exp2f(t * 1.4426950408889634f);  // e^t, >= 1 for t >= 0
    int b = (int)ex - 1;
    return (b > 30) ? 30 : b;
}

__global__ __launch_bounds__(256) void hist_kernel(const float* __restrict__ target,
                                                   unsigned int* __restrict__ g_counts,
                                                   int n4) {
    __shared__ unsigned int lh[NROW * HS];   // 16896 B
    __shared__ unsigned int part[4][32];
    __shared__ unsigned int vpart[4];
    const int tid = threadIdx.x;

    for (int k = tid; k < NROW * HS; k += NTHR) lh[k] = 0u;
    __syncthreads();

    unsigned int cval = 0;
    const float4* t4 = (const float4*)target;
    const int tbase = (tid & (NROW - 1)) * HS;
    for (int i = blockIdx.x * NTHR + tid; i < n4; i += NBLK * NTHR) {
        float4 v = t4[i];
#pragma unroll
        for (int e = 0; e < 4; ++e) {
            float t = (&v.x)[e];
            cval += (t != -1.0f) ? 1u : 0u;
            int b = (t >= 0.0f) ? fast_bin(t) : 31;   // slot 31 = dummy (branchless)
            atomicAdd(&lh[tbase + b], 1u);            // ds_add_u32, no return: fire-and-forget
        }
    }

    // valid count: wave shuffle reduce (before the barrier, independent of lh)
#pragma unroll
    for (int off = 32; off > 0; off >>= 1) cval += __shfl_down(cval, off, 64);
    if ((tid & 63) == 0) vpart[tid >> 6] = cval;
    __syncthreads();

    // stage 1: 4 groups x 31 bins; group g sums rows [g*32, g*32+32)
    if (tid < NROW) {
        int b = tid & 31, g = tid >> 5;
        if (b < 31) {
            unsigned int s = 0;
#pragma unroll 8
            for (int r = g * 32; r < g * 32 + 32; ++r) s += lh[r * HS + b];
            part[g][b] = s;
        }
    }
    __syncthreads();
    if (tid < 31) atomicAdd(&g_counts[tid], part[0][tid] + part[1][tid] + part[2][tid] + part[3][tid]);
    if (tid == 32) atomicAdd(&g_counts[31], vpart[0] + vpart[1] + vpart[2] + vpart[3]);
}

__global__ __launch_bounds__(256) void wsum_kernel(const float* __restrict__ pred,
                                                   const float* __restrict__ target,
                                                   const unsigned int* __restrict__ g_counts,
                                                   float* __restrict__ partials,
                                                   int n4) {
    __shared__ float w_s[31];
    __shared__ float red[4];
    const int tid = threadIdx.x;
    if (tid < 31) {
        float tv   = (float)g_counts[31];
        float freq = (float)g_counts[tid] / tv;
        w_s[tid]   = 1.0f / (sqrtf(freq) + 1e-6f);   // ALPHA=0.5, EPS=1e-6
    }
    __syncthreads();

    float s = 0.0f;
    const float4* t4 = (const float4*)target;
    const float4* p4 = (const float4*)pred;
    for (int i = blockIdx.x * NTHR + tid; i < n4; i += NBLK * NTHR) {
        float4 tv4 = t4[i];
        float4 pv4 = p4[i];
#pragma unroll
        for (int e = 0; e < 4; ++e) {
            float t = (&tv4.x)[e];
            float p = (&pv4.x)[e];
            if (t >= 0.0f) {
                s += fabsf(p - t) * w_s[fast_bin(t)];  // <=2 lanes/bank + broadcast: free
            }
        }
    }
#pragma unroll
    for (int off = 32; off > 0; off >>= 1) s += __shfl_down(s, off, 64);
    if ((tid & 63) == 0) red[tid >> 6] = s;
    __syncthreads();
    if (tid == 0) partials[blockIdx.x] = red[0] + red[1] + red[2] + red[3];
}

__global__ __launch_bounds__(256) void final_kernel(const float* __restrict__ partials,
                                                    const unsigned int* __restrict__ g_counts,
                                                    float* __restrict__ out, int nblk) {
    __shared__ float red[4];
    const int tid = threadIdx.x;
    float s = 0.0f;
    for (int i = tid; i < nblk; i += 256) s += partials[i];
#pragma unroll
    for (int off = 32; off > 0; off >>= 1) s += __shfl_down(s, off, 64);
    if ((tid & 63) == 0) red[tid >> 6] = s;
    __syncthreads();
    if (tid == 0) out[0] = (red[0] + red[1] + red[2] + red[3]) / (float)g_counts[31];
}

extern "C" void kernel_launch(void* const* d_in, const int* in_sizes, int n_in,
                              void* d_out, int out_size, void* d_ws, size_t ws_size,
                              hipStream_t stream) {
    const float* pred   = (const float*)d_in[0];
    const float* target = (const float*)d_in[1];
    float*       out    = (float*)d_out;

    unsigned int* g_counts = (unsigned int*)d_ws;              // 32 uints
    float*        partials = (float*)((char*)d_ws + 128);      // NBLK floats

    const int n  = in_sizes[0];    // 16,777,216; NBLK*NTHR*4 divides n exactly
    const int n4 = n / 4;

    hipMemsetAsync(d_ws, 0, 128, stream);                      // zero counts each call
    hist_kernel<<<NBLK, NTHR, 0, stream>>>(target, g_counts, n4);
    wsum_kernel<<<NBLK, NTHR, 0, stream>>>(pred, target, g_counts, partials, n4);
    final_kernel<<<1, NTHR, 0, stream>>>(partials, g_counts, out, NBLK);
}

// Round 4
// 76.143 us; speedup vs baseline: 3.3283x; 1.1727x over previous
//
#include <hip/hip_runtime.h>
#include <math.h>

// RangeAwareL1Loss on MI355X — fused single pass.
// loss = sum_b S[b]*w[b] / total_valid, S[b] = sum_{bin b} |p-t| (independent of w).
// Per-element: one ds_add_u64 of (count=1 << 40 | fixed22(|p-t|)) into a row-private bin.
// ws layout: [0..30] u32 bin counts, [31] u32 valid count; byte 128+: 31 u64 fixed sums.

#define NBLK   2048
#define NTHR   256
#define NROW   64                  // rows shared by 4 threads (tid & 63): in-wave lanes distinct
#define HS     33                  // u64 stride: ~4-way banking, free-ish
#define FSCALE 4194304.0f          // 2^22 fixed point
#define CSHIFT 40                  // count field at bits [40..]

// fast bin: for t >= 0, floor(expm1(t)) == floor(exp(t)) - 1 == (int)exp2(t*log2e) - 1
__device__ __forceinline__ int fast_bin(float t) {
    float ex = __builtin_amdgcn_exp2f(t * 1.4426950408889634f);
    int b = (int)ex - 1;
    return (b > 30) ? 30 : b;
}

__device__ __forceinline__ void process_elem(float t, float p, unsigned int& cval,
                                             unsigned long long* lh, int row) {
    cval += (t != -1.0f) ? 1u : 0u;
    int b = (t >= 0.0f) ? fast_bin(t) : 31;              // slot 31 = dummy (branchless)
    unsigned int fx = (unsigned int)(fabsf(p - t) * FSCALE);
    atomicAdd(&lh[row + b], (1ull << CSHIFT) | (unsigned long long)fx);  // ds_add_u64
}

__global__ __launch_bounds__(256) void fused_kernel(const float* __restrict__ pred,
                                                    const float* __restrict__ target,
                                                    unsigned int* __restrict__ g_counts,
                                                    unsigned long long* __restrict__ g_sums,
                                                    int n4) {
    __shared__ unsigned long long lh[NROW * HS + 32];    // 17 KB (+pad for slot 31 of last row)
    __shared__ unsigned int vpart[4];
    const int tid = threadIdx.x;

    for (int k = tid; k < NROW * HS + 32; k += NTHR) lh[k] = 0ull;
    __syncthreads();

    unsigned int cval = 0;
    const float4* t4 = (const float4*)target;
    const float4* p4 = (const float4*)pred;
    const int row = (tid & (NROW - 1)) * HS;
    const int S = NBLK * NTHR;

    int i = blockIdx.x * NTHR + tid;
    // 4x unroll: 8 independent 16B loads in flight per thread (MLP — the R2 bottleneck)
    for (; i + 3 * S < n4; i += 4 * S) {
        float4 tv0 = t4[i],         tv1 = t4[i + S],
               tv2 = t4[i + 2 * S], tv3 = t4[i + 3 * S];
        float4 pv0 = p4[i],         pv1 = p4[i + S],
               pv2 = p4[i + 2 * S], pv3 = p4[i + 3 * S];
#pragma unroll
        for (int e = 0; e < 4; ++e) process_elem((&tv0.x)[e], (&pv0.x)[e], cval, lh, row);
#pragma unroll
        for (int e = 0; e < 4; ++e) process_elem((&tv1.x)[e], (&pv1.x)[e], cval, lh, row);
#pragma unroll
        for (int e = 0; e < 4; ++e) process_elem((&tv2.x)[e], (&pv2.x)[e], cval, lh, row);
#pragma unroll
        for (int e = 0; e < 4; ++e) process_elem((&tv3.x)[e], (&pv3.x)[e], cval, lh, row);
    }
    for (; i < n4; i += S) {                             // tail (empty at bench shape)
        float4 tv = t4[i], pv = p4[i];
#pragma unroll
        for (int e = 0; e < 4; ++e) process_elem((&tv.x)[e], (&pv.x)[e], cval, lh, row);
    }

    // valid-count wave reduce (independent of lh)
#pragma unroll
    for (int off = 32; off > 0; off >>= 1) cval += __shfl_down(cval, off, 64);
    if ((tid & 63) == 0) vpart[tid >> 6] = cval;
    __syncthreads();

    // reduce 64 rows x 31 bins; fields can't carry: sum<=64*2^31<2^40, count<=8192
    if (tid < 31) {
        unsigned long long s = 0;
#pragma unroll 8
        for (int r = 0; r < NROW; ++r) s += lh[r * HS + tid];
        atomicAdd(&g_counts[tid], (unsigned int)(s >> CSHIFT));
        atomicAdd(&g_sums[tid], s & ((1ull << CSHIFT) - 1ull));
    }
    if (tid == 32) atomicAdd(&g_counts[31], vpart[0] + vpart[1] + vpart[2] + vpart[3]);
}

__global__ __launch_bounds__(64) void final_kernel(const unsigned int* __restrict__ g_counts,
                                                   const unsigned long long* __restrict__ g_sums,
                                                   float* __restrict__ out) {
    const int tid = threadIdx.x;
    double term = 0.0;
    float tv = (float)g_counts[31];
    if (tid < 31) {
        float freq = (float)g_counts[tid] / tv;          // f32, matching reference numerics
        float w    = 1.0f / (sqrtf(freq) + 1e-6f);       // ALPHA=0.5, EPS=1e-6
        term = (double)g_sums[tid] * (double)w;
    }
#pragma unroll
    for (int off = 32; off > 0; off >>= 1) term += __shfl_down(term, off, 64);
    if (tid == 0) out[0] = (float)(term / 4194304.0 / (double)tv);
}

extern "C" void kernel_launch(void* const* d_in, const int* in_sizes, int n_in,
                              void* d_out, int out_size, void* d_ws, size_t ws_size,
                              hipStream_t stream) {
    const float* pred   = (const float*)d_in[0];
    const float* target = (const float*)d_in[1];
    float*       out    = (float*)d_out;

    unsigned int*       g_counts = (unsigned int*)d_ws;               // 32 u32
    unsigned long long* g_sums   = (unsigned long long*)((char*)d_ws + 128);  // 31 u64

    const int n  = in_sizes[0];   // 16,777,216
    const int n4 = n / 4;

    hipMemsetAsync(d_ws, 0, 512, stream);
    fused_kernel<<<NBLK, NTHR, 0, stream>>>(pred, target, g_counts, g_sums, n4);
    final_kernel<<<1, 64, 0, stream>>>(g_counts, g_sums, out);
}

// Round 5
// 47.111 us; speedup vs baseline: 5.3793x; 1.6162x over previous
//
#include <hip/hip_runtime.h>
#include <math.h>

// RangeAwareL1Loss on MI355X — fused single pass, NO same-line global atomics.
// Per block: 31 packed u64 (count<<40 | fixed22-sum) + valid count -> g_part[bid*32+..].
// Stage 2: one 1024-thread block reduces 2048x32 and computes the loss.

#define NBLK   2048
#define NTHR   256
#define NROW   64                  // rows shared by 4 threads (tid & 63): in-wave lanes distinct
#define HS     33                  // u64 stride: ~4-way banking (free-ish)
#define FSCALE 4194304.0f          // 2^22 fixed point
#define CSHIFT 40                  // count field at bits [40..]

// fast bin: for t >= 0, floor(expm1(t)) == floor(exp(t)) - 1 == (int)exp2(t*log2e) - 1
__device__ __forceinline__ int fast_bin(float t) {
    float ex = __builtin_amdgcn_exp2f(t * 1.4426950408889634f);
    int b = (int)ex - 1;
    return (b > 30) ? 30 : b;
}

__global__ __launch_bounds__(256) void fused_kernel(const float* __restrict__ pred,
                                                    const float* __restrict__ target,
                                                    unsigned long long* __restrict__ g_part,
                                                    int n4, int nblk) {
    __shared__ unsigned long long lh[NROW * HS + 32];    // ~17 KB (+pad: slot 31 of last row)
    __shared__ unsigned int vpart[4];
    const int tid = threadIdx.x;

    for (int k = tid; k < NROW * HS + 32; k += NTHR) lh[k] = 0ull;
    __syncthreads();

    unsigned int cval = 0;
    const float4* t4 = (const float4*)target;
    const float4* p4 = (const float4*)pred;
    const int row = (tid & (NROW - 1)) * HS;

    for (int i = blockIdx.x * NTHR + tid; i < n4; i += nblk * NTHR) {
        float4 tv = t4[i];
        float4 pv = p4[i];
#pragma unroll
        for (int e = 0; e < 4; ++e) {
            float t = (&tv.x)[e];
            float p = (&pv.x)[e];
            cval += (t != -1.0f) ? 1u : 0u;
            int b = (t >= 0.0f) ? fast_bin(t) : 31;          // slot 31 = dummy (branchless)
            unsigned int fx = (unsigned int)(fabsf(p - t) * FSCALE);
            atomicAdd(&lh[row + b], (1ull << CSHIFT) | (unsigned long long)fx);
        }
    }

    // valid-count wave reduce (independent of lh)
#pragma unroll
    for (int off = 32; off > 0; off >>= 1) cval += __shfl_down(cval, off, 64);
    if ((tid & 63) == 0) vpart[tid >> 6] = cval;
    __syncthreads();

    // block reduce 64 rows x 31 bins, then ONE coalesced 256B store. No global atomics.
    if (tid < 32) {
        unsigned long long s = 0;
        if (tid < 31) {
#pragma unroll 8
            for (int r = 0; r < NROW; ++r) s += lh[r * HS + tid];
        } else {
            s = (unsigned long long)(vpart[0] + vpart[1] + vpart[2] + vpart[3]);
        }
        g_part[blockIdx.x * 32 + tid] = s;
    }
}

__global__ __launch_bounds__(1024) void reduce_kernel(const unsigned long long* __restrict__ g_part,
                                                      float* __restrict__ out, int nblk) {
    __shared__ unsigned long long ssum[32][32];   // 8 KB
    __shared__ unsigned int      scnt[32][32];    // 4 KB
    const int tid = threadIdx.x;
    const int col = tid & 31, grp = tid >> 5;

    unsigned long long sum = 0;  // col 31 rows hold raw valid counts -> land in sum (count=0)
    unsigned int cnt = 0;
    for (int r = grp; r < nblk; r += 32) {        // wave reads 2 consecutive rows: coalesced
        unsigned long long v = g_part[r * 32 + col];
        sum += v & ((1ull << CSHIFT) - 1ull);     // unpack per-block: totals would overflow packed
        cnt += (unsigned int)(v >> CSHIFT);
    }
    ssum[grp][col] = sum;
    scnt[grp][col] = cnt;
    __syncthreads();

    if (tid < 64) {
        unsigned long long s = 0;
        unsigned int c = 0;
        if (tid < 32) {
#pragma unroll
            for (int g = 0; g < 32; ++g) { s += ssum[g][tid]; c += scnt[g][tid]; }
        }
        float tv = (float)(unsigned long long)__shfl((long long)s, 31, 64);  // lane 31 = total valid
        double term = 0.0;
        if (tid < 31) {
            float freq = (float)c / tv;                  // f32, matching reference numerics
            float w    = 1.0f / (sqrtf(freq) + 1e-6f);   // ALPHA=0.5, EPS=1e-6
            term = (double)s * (double)w;
        }
#pragma unroll
        for (int off = 32; off > 0; off >>= 1) term += __shfl_down(term, off, 64);
        if (tid == 0) out[0] = (float)(term / 4194304.0 / (double)tv);
    }
}

extern "C" void kernel_launch(void* const* d_in, const int* in_sizes, int n_in,
                              void* d_out, int out_size, void* d_ws, size_t ws_size,
                              hipStream_t stream) {
    const float* pred   = (const float*)d_in[0];
    const float* target = (const float*)d_in[1];
    float*       out    = (float*)d_out;

    unsigned long long* g_part = (unsigned long long*)d_ws;   // nblk * 32 u64

    const int n  = in_sizes[0];   // 16,777,216
    const int n4 = n / 4;

    int nblk = NBLK;
    size_t need = (size_t)nblk * 32 * sizeof(unsigned long long);
    if (ws_size < need) nblk = (int)(ws_size / (32 * sizeof(unsigned long long)));  // grid-stride covers any nblk

    fused_kernel<<<nblk, NTHR, 0, stream>>>(pred, target, g_part, n4, nblk);
    reduce_kernel<<<1, 1024, 0, stream>>>(g_part, out, nblk);
}